// Round 1
// baseline (797.793 us; speedup 1.0000x reference)
//
#include <hip/hip_runtime.h>
#include <hip/hip_bf16.h>
#include <stdint.h>

#define E_DIM 1024
#define H_NUM 16
#define HD_DIM 64
#define B_NUM 8
#define SENG 2048
#define SCHI 1024

typedef __attribute__((ext_vector_type(4))) float f32x4;
typedef __attribute__((ext_vector_type(8))) short bf16x8;
typedef __attribute__((ext_vector_type(8))) unsigned short u16x8;
typedef __attribute__((ext_vector_type(4))) unsigned short u16x4;

__device__ __forceinline__ unsigned short f2bf(float f) {
  unsigned int u = __builtin_bit_cast(unsigned int, f);
  u = (u + 0x7fffu + ((u >> 16) & 1u)) >> 16;  // RNE
  return (unsigned short)u;
}

__device__ __forceinline__ void gload_lds16(const void* g, void* l) {
  __builtin_amdgcn_global_load_lds(
      (const __attribute__((address_space(1))) unsigned int*)g,
      (__attribute__((address_space(3))) unsigned int*)l, 16, 0, 0);
}

// ---------------- f32 -> bf16 cast (8 elems/thread) ----------------
__global__ __launch_bounds__(256) void cast_bf16_k(const float* __restrict__ in,
                                                   unsigned short* __restrict__ out,
                                                   int n) {
  int i = (blockIdx.x * 256 + threadIdx.x) * 8;
  if (i >= n) return;
  float4 a = *(const float4*)(in + i);
  float4 b = *(const float4*)(in + i + 4);
  u16x8 v;
  v[0] = f2bf(a.x); v[1] = f2bf(a.y); v[2] = f2bf(a.z); v[3] = f2bf(a.w);
  v[4] = f2bf(b.x); v[5] = f2bf(b.y); v[6] = f2bf(b.z); v[7] = f2bf(b.w);
  *(u16x8*)(out + i) = v;
}

// ---- Wq/Wk/Wv [H][E][HD] f32 -> WT [N=h*64+d][K=e] bf16 (B^T layout) ----
__global__ __launch_bounds__(256) void pack_w_qkv(const float* __restrict__ w,
                                                  unsigned short* __restrict__ wt) {
  int t = blockIdx.x * 256 + threadIdx.x;  // t = n*1024 + e
  int e = t & 1023;
  int n = t >> 10;
  int h = n >> 6, d = n & 63;
  wt[t] = f2bf(w[(h * E_DIM + e) * HD_DIM + d]);
}

// ---- Wo [E][E] f32 -> WoT [n][k] = Wo[k][n] bf16 ----
__global__ __launch_bounds__(256) void pack_wo(const float* __restrict__ w,
                                               unsigned short* __restrict__ wt) {
  int t = blockIdx.x * 256 + threadIdx.x;  // t = n*1024 + k
  int k = t & 1023;
  int n = t >> 10;
  wt[t] = f2bf(w[k * E_DIM + n]);
}

// ---------------- GEMM: C = A[M,K] * Bt[N,K]^T ----------------
// MODE 0: C bf16 row-major [M][N]
// MODE 1: C f32  row-major [M][N]
// MODE 2: C bf16 scattered into Vt[(b*16+h)*64+d][kk], row=b*SENG+kk, col=h*64+d
template <int MODE>
__global__ __launch_bounds__(256) void gemm_bt(const unsigned short* __restrict__ A,
                                               const unsigned short* __restrict__ Bt,
                                               void* __restrict__ Cv,
                                               int M, int N, int K) {
  __shared__ unsigned short As[128 * 32];
  __shared__ unsigned short Bs[128 * 32];
  const int tid = threadIdx.x;
  const int w = tid >> 6, lane = tid & 63;
  const int bm = blockIdx.y, bn = blockIdx.x;
  const int wm = w >> 1, wn = w & 1;
  const int rl = lane & 15, gl = lane >> 4;
  f32x4 acc[4][4] = {};

  const int lr = lane >> 2, lc = lane & 3;  // 16 rows x 4 chunks per wave-load
  const unsigned short* Ag = A + (size_t)(bm * 128 + w * 32 + lr) * K + lc * 8;
  const unsigned short* Bg = Bt + (size_t)(bn * 128 + w * 32 + lr) * K + lc * 8;
  unsigned short* Asw = As + w * 32 * 32;  // wave-uniform LDS base
  unsigned short* Bsw = Bs + w * 32 * 32;

  for (int kt = 0; kt < K; kt += 32) {
    gload_lds16(Ag + kt, Asw);
    gload_lds16(Ag + kt + 16 * K, Asw + 16 * 32);
    gload_lds16(Bg + kt, Bsw);
    gload_lds16(Bg + kt + 16 * K, Bsw + 16 * 32);
    __syncthreads();
    bf16x8 af[4], bfr[4];
#pragma unroll
    for (int mt = 0; mt < 4; ++mt)
      af[mt] = *(const bf16x8*)&As[(wm * 64 + mt * 16 + rl) * 32 + gl * 8];
#pragma unroll
    for (int nt = 0; nt < 4; ++nt)
      bfr[nt] = *(const bf16x8*)&Bs[(wn * 64 + nt * 16 + rl) * 32 + gl * 8];
#pragma unroll
    for (int mt = 0; mt < 4; ++mt)
#pragma unroll
      for (int nt = 0; nt < 4; ++nt)
        acc[mt][nt] =
            __builtin_amdgcn_mfma_f32_16x16x32_bf16(af[mt], bfr[nt], acc[mt][nt], 0, 0, 0);
    __syncthreads();
  }

#pragma unroll
  for (int mt = 0; mt < 4; ++mt)
#pragma unroll
    for (int nt = 0; nt < 4; ++nt) {
      const int row0 = bm * 128 + wm * 64 + mt * 16 + gl * 4;
      const int col = bn * 128 + wn * 64 + nt * 16 + rl;
      if (MODE == 0) {
        unsigned short* C = (unsigned short*)Cv;
#pragma unroll
        for (int r = 0; r < 4; ++r) C[(size_t)(row0 + r) * N + col] = f2bf(acc[mt][nt][r]);
      } else if (MODE == 1) {
        float* C = (float*)Cv;
#pragma unroll
        for (int r = 0; r < 4; ++r) C[(size_t)(row0 + r) * N + col] = acc[mt][nt][r];
      } else {
        unsigned short* Vt = (unsigned short*)Cv;
        const int b = row0 >> 11, kk = row0 & 2047;  // SENG = 2048
        const int h = col >> 6, d = col & 63;
        u16x4 pk;
#pragma unroll
        for (int r = 0; r < 4; ++r) pk[r] = f2bf(acc[mt][nt][r]);
        *(u16x4*)(Vt + (size_t)((b * 16 + h) * 64 + d) * SENG + kk) = pk;
      }
    }
}

// ---------------- flash attention ----------------
// grid: (bh=128, qb=16), 256 thr (4 waves x 16 q-rows). KB=64 keys/iter.
__global__ __launch_bounds__(256) void flash_attn(const unsigned short* __restrict__ Qf,
                                                  const unsigned short* __restrict__ Kf,
                                                  const unsigned short* __restrict__ Vt,
                                                  unsigned short* __restrict__ att) {
  const int bh = blockIdx.x, qb = blockIdx.y;
  const int b = bh >> 4, h = bh & 15;
  const int w = threadIdx.x >> 6, lane = threadIdx.x & 63;
  const int rl = lane & 15, gl = lane >> 4;
  __shared__ unsigned short Plds[4][16][64];  // per-wave P tile

  const int q0 = qb * 64 + w * 16;
  const unsigned short* Qp = Qf + (size_t)(b * SCHI + q0 + rl) * E_DIM + h * HD_DIM + gl * 8;
  const bf16x8 qf0 = *(const bf16x8*)Qp;
  const bf16x8 qf1 = *(const bf16x8*)(Qp + 32);

  const unsigned short* Kb = Kf + (size_t)(b * SENG) * E_DIM + h * HD_DIM + gl * 8;
  const unsigned short* Vb = Vt + (size_t)bh * HD_DIM * SENG;  // [d][kk]

  f32x4 o[4] = {};
  float m_run[4], l_run[4];
#pragma unroll
  for (int r = 0; r < 4; ++r) { m_run[r] = -1e30f; l_run[r] = 0.f; }
  const float Cs = 0.125f * 1.44269504f;  // 1/sqrt(64) * log2(e)

  for (int k0 = 0; k0 < SENG; k0 += 64) {
    f32x4 s[4];
#pragma unroll
    for (int t = 0; t < 4; ++t) {
      const unsigned short* kp = Kb + (size_t)(k0 + t * 16 + rl) * E_DIM;
      bf16x8 kf0 = *(const bf16x8*)kp;
      bf16x8 kf1 = *(const bf16x8*)(kp + 32);
      f32x4 z = {};
      z = __builtin_amdgcn_mfma_f32_16x16x32_bf16(qf0, kf0, z, 0, 0, 0);
      z = __builtin_amdgcn_mfma_f32_16x16x32_bf16(qf1, kf1, z, 0, 0, 0);
      s[t] = z;
    }
    float al[4];
#pragma unroll
    for (int r = 0; r < 4; ++r) {
      float v = fmaxf(fmaxf(s[0][r], s[1][r]), fmaxf(s[2][r], s[3][r]));
      v = fmaxf(v, __shfl_xor(v, 1));
      v = fmaxf(v, __shfl_xor(v, 2));
      v = fmaxf(v, __shfl_xor(v, 4));
      v = fmaxf(v, __shfl_xor(v, 8));
      const float mnew = fmaxf(m_run[r], v * Cs);
      al[r] = exp2f(m_run[r] - mnew);
      m_run[r] = mnew;
    }
#pragma unroll
    for (int r = 0; r < 4; ++r) {
      const float m = m_run[r];
      float p0 = exp2f(fmaf(s[0][r], Cs, -m));
      float p1 = exp2f(fmaf(s[1][r], Cs, -m));
      float p2 = exp2f(fmaf(s[2][r], Cs, -m));
      float p3 = exp2f(fmaf(s[3][r], Cs, -m));
      Plds[w][gl * 4 + r][0 + rl] = f2bf(p0);
      Plds[w][gl * 4 + r][16 + rl] = f2bf(p1);
      Plds[w][gl * 4 + r][32 + rl] = f2bf(p2);
      Plds[w][gl * 4 + r][48 + rl] = f2bf(p3);
      float t = (p0 + p1) + (p2 + p3);
      t += __shfl_xor(t, 1);
      t += __shfl_xor(t, 2);
      t += __shfl_xor(t, 4);
      t += __shfl_xor(t, 8);
      l_run[r] = l_run[r] * al[r] + t;
    }
#pragma unroll
    for (int nt = 0; nt < 4; ++nt)
#pragma unroll
      for (int r = 0; r < 4; ++r) o[nt][r] *= al[r];
#pragma unroll
    for (int ks = 0; ks < 2; ++ks) {
      const bf16x8 pf = *(const bf16x8*)&Plds[w][rl][ks * 32 + gl * 8];
#pragma unroll
      for (int nt = 0; nt < 4; ++nt) {
        const bf16x8 vf =
            *(const bf16x8*)(Vb + (size_t)(nt * 16 + rl) * SENG + k0 + ks * 32 + gl * 8);
        o[nt] = __builtin_amdgcn_mfma_f32_16x16x32_bf16(pf, vf, o[nt], 0, 0, 0);
      }
    }
  }

  unsigned short* ob = att + (size_t)(b * SCHI + q0) * E_DIM + h * HD_DIM;
#pragma unroll
  for (int r = 0; r < 4; ++r) {
    const float inv = 1.0f / l_run[r];
#pragma unroll
    for (int nt = 0; nt < 4; ++nt)
      ob[(size_t)(gl * 4 + r) * E_DIM + nt * 16 + rl] = f2bf(o[nt][r] * inv);
  }
}

extern "C" void kernel_launch(void* const* d_in, const int* in_sizes, int n_in,
                              void* d_out, int out_size, void* d_ws, size_t ws_size,
                              hipStream_t stream) {
  const float* eng = (const float*)d_in[0];
  const float* chi = (const float*)d_in[1];
  const float* Wq = (const float*)d_in[2];
  const float* Wk = (const float*)d_in[3];
  const float* Wv = (const float*)d_in[4];
  const float* Wo = (const float*)d_in[5];
  float* out = (float*)d_out;

  char* ws = (char*)d_ws;
  const size_t MB = 1024 * 1024;
  unsigned short* WqT = (unsigned short*)(ws + 0 * MB);    // 2 MB
  unsigned short* WkT = (unsigned short*)(ws + 2 * MB);    // 2 MB
  unsigned short* WvT = (unsigned short*)(ws + 4 * MB);    // 2 MB
  unsigned short* WoT = (unsigned short*)(ws + 6 * MB);    // 2 MB
  unsigned short* Xc = (unsigned short*)(ws + 8 * MB);     // 16 MB (reused as att)
  unsigned short* Xe = (unsigned short*)(ws + 24 * MB);    // 32 MB
  unsigned short* Qf = (unsigned short*)(ws + 56 * MB);    // 16 MB
  unsigned short* Kf = (unsigned short*)(ws + 72 * MB);    // 32 MB
  unsigned short* Vt = (unsigned short*)(ws + 104 * MB);   // 32 MB  -> total 136 MB
  unsigned short* att = Xc;  // Xc dead after Q-GEMM

  pack_w_qkv<<<4096, 256, 0, stream>>>(Wq, WqT);
  pack_w_qkv<<<4096, 256, 0, stream>>>(Wk, WkT);
  pack_w_qkv<<<4096, 256, 0, stream>>>(Wv, WvT);
  pack_wo<<<4096, 256, 0, stream>>>(Wo, WoT);

  cast_bf16_k<<<(B_NUM * SCHI * E_DIM / 8) / 256, 256, 0, stream>>>(chi, Xc, B_NUM * SCHI * E_DIM);
  cast_bf16_k<<<(B_NUM * SENG * E_DIM / 8) / 256, 256, 0, stream>>>(eng, Xe, B_NUM * SENG * E_DIM);

  gemm_bt<0><<<dim3(8, 64), 256, 0, stream>>>(Xc, WqT, (void*)Qf, B_NUM * SCHI, E_DIM, E_DIM);
  gemm_bt<0><<<dim3(8, 128), 256, 0, stream>>>(Xe, WkT, (void*)Kf, B_NUM * SENG, E_DIM, E_DIM);
  gemm_bt<2><<<dim3(8, 128), 256, 0, stream>>>(Xe, WvT, (void*)Vt, B_NUM * SENG, E_DIM, E_DIM);

  flash_attn<<<dim3(128, 16), 256, 0, stream>>>(Qf, Kf, Vt, att);

  gemm_bt<1><<<dim3(8, 64), 256, 0, stream>>>(att, WoT, (void*)out, B_NUM * SCHI, E_DIM, E_DIM);
}

// Round 6
// 584.508 us; speedup vs baseline: 1.3649x; 1.3649x over previous
//
#include <hip/hip_runtime.h>
#include <hip/hip_bf16.h>
#include <stdint.h>

#define E_DIM 1024
#define H_NUM 16
#define HD_DIM 64
#define B_NUM 8
#define SENG 2048
#define SCHI 1024

typedef __attribute__((ext_vector_type(4))) float f32x4;
typedef __attribute__((ext_vector_type(8))) short bf16x8;
typedef __attribute__((ext_vector_type(8))) unsigned short u16x8;
typedef __attribute__((ext_vector_type(4))) unsigned short u16x4;

__device__ __forceinline__ unsigned short f2bf(float f) {
  unsigned int u = __builtin_bit_cast(unsigned int, f);
  u = (u + 0x7fffu + ((u >> 16) & 1u)) >> 16;  // RNE
  return (unsigned short)u;
}

__device__ __forceinline__ void gload_lds16(const void* g, void* l) {
  __builtin_amdgcn_global_load_lds(
      (const __attribute__((address_space(1))) unsigned int*)g,
      (__attribute__((address_space(3))) unsigned int*)l, 16, 0, 0);
}

// ---------------- f32 -> bf16 cast (8 elems/thread) ----------------
__global__ __launch_bounds__(256) void cast_bf16_k(const float* __restrict__ in,
                                                   unsigned short* __restrict__ out,
                                                   int n) {
  int i = (blockIdx.x * 256 + threadIdx.x) * 8;
  if (i >= n) return;
  float4 a = *(const float4*)(in + i);
  float4 b = *(const float4*)(in + i + 4);
  u16x8 v;
  v[0] = f2bf(a.x); v[1] = f2bf(a.y); v[2] = f2bf(a.z); v[3] = f2bf(a.w);
  v[4] = f2bf(b.x); v[5] = f2bf(b.y); v[6] = f2bf(b.z); v[7] = f2bf(b.w);
  *(u16x8*)(out + i) = v;
}

// ---- Wq/Wk/Wv [H][E][HD] f32 -> WT [N=h*64+d][K=e] bf16 (B^T layout) ----
__global__ __launch_bounds__(256) void pack_w_qkv(const float* __restrict__ w,
                                                  unsigned short* __restrict__ wt) {
  int t = blockIdx.x * 256 + threadIdx.x;  // t = n*1024 + e
  int e = t & 1023;
  int n = t >> 10;
  int h = n >> 6, d = n & 63;
  wt[t] = f2bf(w[(h * E_DIM + e) * HD_DIM + d]);
}

// ---- Wo [E][E] f32 -> WoT [n][k] = Wo[k][n] bf16 ----
__global__ __launch_bounds__(256) void pack_wo(const float* __restrict__ w,
                                               unsigned short* __restrict__ wt) {
  int t = blockIdx.x * 256 + threadIdx.x;  // t = n*1024 + k
  int k = t & 1023;
  int n = t >> 10;
  wt[t] = f2bf(w[k * E_DIM + n]);
}

// ---------------- GEMM: C = A[M,K] * Bt[N,K]^T ----------------
// MODE 1: C f32 row-major [M][N]
// MODE 2: C bf16 into Vt[bh][d][kk]   (row=b*SENG+kk, col=h*64+d)
// MODE 3: C bf16 into Qh[bh][q][d]    (row=b*SCHI+q,  col=h*64+d)
// MODE 4: C bf16 into Kh[bh][kk][d]   (row=b*SENG+kk, col=h*64+d)
template <int MODE>
__global__ __launch_bounds__(256) void gemm_bt(const unsigned short* __restrict__ A,
                                               const unsigned short* __restrict__ Bt,
                                               void* __restrict__ Cv,
                                               int M, int N, int K) {
  __shared__ unsigned short As[128 * 32];
  __shared__ unsigned short Bs[128 * 32];
  const int tid = threadIdx.x;
  const int w = tid >> 6, lane = tid & 63;
  const int bm = blockIdx.y, bn = blockIdx.x;
  const int wm = w >> 1, wn = w & 1;
  const int rl = lane & 15, gl = lane >> 4;
  f32x4 acc[4][4] = {};

  const int lr = lane >> 2, lc = lane & 3;  // 16 rows x 4 chunks per wave-load
  const unsigned short* Ag = A + (size_t)(bm * 128 + w * 32 + lr) * K + lc * 8;
  const unsigned short* Bg = Bt + (size_t)(bn * 128 + w * 32 + lr) * K + lc * 8;
  unsigned short* Asw = As + w * 32 * 32;  // wave-uniform LDS base
  unsigned short* Bsw = Bs + w * 32 * 32;

  for (int kt = 0; kt < K; kt += 32) {
    gload_lds16(Ag + kt, Asw);
    gload_lds16(Ag + kt + 16 * K, Asw + 16 * 32);
    gload_lds16(Bg + kt, Bsw);
    gload_lds16(Bg + kt + 16 * K, Bsw + 16 * 32);
    __syncthreads();
    bf16x8 af[4], bfr[4];
#pragma unroll
    for (int mt = 0; mt < 4; ++mt)
      af[mt] = *(const bf16x8*)&As[(wm * 64 + mt * 16 + rl) * 32 + gl * 8];
#pragma unroll
    for (int nt = 0; nt < 4; ++nt)
      bfr[nt] = *(const bf16x8*)&Bs[(wn * 64 + nt * 16 + rl) * 32 + gl * 8];
#pragma unroll
    for (int mt = 0; mt < 4; ++mt)
#pragma unroll
      for (int nt = 0; nt < 4; ++nt)
        acc[mt][nt] =
            __builtin_amdgcn_mfma_f32_16x16x32_bf16(af[mt], bfr[nt], acc[mt][nt], 0, 0, 0);
    __syncthreads();
  }

#pragma unroll
  for (int mt = 0; mt < 4; ++mt)
#pragma unroll
    for (int nt = 0; nt < 4; ++nt) {
      const int row0 = bm * 128 + wm * 64 + mt * 16 + gl * 4;
      const int col = bn * 128 + wn * 64 + nt * 16 + rl;
      if (MODE == 1) {
        float* C = (float*)Cv;
#pragma unroll
        for (int r = 0; r < 4; ++r) C[(size_t)(row0 + r) * N + col] = acc[mt][nt][r];
      } else if (MODE == 2) {
        unsigned short* Vt = (unsigned short*)Cv;
        const int b = row0 >> 11, kk = row0 & 2047;
        const int h = col >> 6, d = col & 63;
        u16x4 pk;
#pragma unroll
        for (int r = 0; r < 4; ++r) pk[r] = f2bf(acc[mt][nt][r]);
        *(u16x4*)(Vt + (size_t)((b * 16 + h) * 64 + d) * SENG + kk) = pk;
      } else if (MODE == 3) {
        unsigned short* Qh = (unsigned short*)Cv;
        const int b = row0 >> 10, q = row0 & 1023;
        const int h = col >> 6, d = col & 63;
        unsigned short* p = Qh + (((size_t)(b * 16 + h) * SCHI + q) * HD_DIM + d);
#pragma unroll
        for (int r = 0; r < 4; ++r) p[(size_t)r * HD_DIM] = f2bf(acc[mt][nt][r]);
      } else {  // MODE 4
        unsigned short* Kh = (unsigned short*)Cv;
        const int b = row0 >> 11, kk = row0 & 2047;
        const int h = col >> 6, d = col & 63;
        unsigned short* p = Kh + (((size_t)(b * 16 + h) * SENG + kk) * HD_DIM + d);
#pragma unroll
        for (int r = 0; r < 4; ++r) p[(size_t)r * HD_DIM] = f2bf(acc[mt][nt][r]);
      }
    }
}

// ---------------- flash attention ----------------
// grid: (bh=128, qb=16), 256 thr (4 waves x 16 q-rows). KB=64 keys/iter.
// K,V tiles LDS-staged (XOR-swizzled via pre-swizzled global source),
// double-buffered. Sync = ONE __syncthreads() per iteration (compiler
// emits vmcnt(0) lgkmcnt(0) + s_barrier -> race-free by construction;
// the raw-asm counted-vmcnt pattern of rounds 2-5 is suspected of a
// mostly-benign staging race producing ~1.3e-3 absmax).
// Softmax arithmetic = round-1 verbatim (always rescale, immediate
// group-reduced l) -> pipeline math is bit-identical to the passing r1.
__global__ __launch_bounds__(256) void flash_attn(const unsigned short* __restrict__ Qh,
                                                  const unsigned short* __restrict__ Kh,
                                                  const unsigned short* __restrict__ Vt,
                                                  unsigned short* __restrict__ att) {
  const int bh = blockIdx.x, qb = blockIdx.y;
  const int b = bh >> 4, h = bh & 15;
  const int w = threadIdx.x >> 6, lane = threadIdx.x & 63;
  const int rl = lane & 15, gl = lane >> 4;

  __shared__ unsigned short Ks[2][4096];      // 2 x 8KB: [krow 64][d 64] swizzled
  __shared__ unsigned short Vs[2][4096];      // 2 x 8KB: [d 64][k 64]   swizzled
  __shared__ unsigned short Plds[4][16][72];  // per-wave P, padded rows

  const unsigned short* Kb = Kh + (size_t)bh * (SENG * HD_DIM);
  const unsigned short* Vb = Vt + (size_t)bh * (HD_DIM * SENG);

  const int q0 = qb * 64 + w * 16;
  const unsigned short* Qp = Qh + ((size_t)bh * SCHI + q0 + rl) * HD_DIM + gl * 8;
  const bf16x8 qf0 = *(const bf16x8*)Qp;
  const bf16x8 qf1 = *(const bf16x8*)(Qp + 32);

  // staging geometry: 16 chunks of 1KB (8 K + 8 V), wave w -> 4 chunks.
  // chunk c covers LDS rows c*8..c*8+7 (128B rows). lane -> (lrow, 16B col),
  // source column pre-swizzled so linear LDS ends up XOR-swizzled:
  // LDS[r][u] = G[r][u^r] in 16B units within each 8-row chunk.
  const int lrow = lane >> 3;                          // 0..7 within chunk
  const int scol = ((lane & 7) ^ lrow) << 3;           // u16 units (swizzled col)

  f32x4 o[4] = {};
  float m_run[4], l_run[4];
#pragma unroll
  for (int r = 0; r < 4; ++r) { m_run[r] = -1e30f; l_run[r] = 0.f; }
  const float Cs = 0.125f * 1.44269504f;  // 1/sqrt(64) * log2(e)

  auto stage = [&](int k0, int bufi) {
    if (w < 2) {
      const int c0 = w * 4;
#pragma unroll
      for (int j = 0; j < 4; ++j) {
        const int c = c0 + j;
        gload_lds16(Kb + (size_t)(k0 + c * 8 + lrow) * HD_DIM + scol, &Ks[bufi][c * 512]);
      }
    } else {
      const int c0 = (w - 2) * 4;
#pragma unroll
      for (int j = 0; j < 4; ++j) {
        const int c = c0 + j;
        gload_lds16(Vb + (size_t)(c * 8 + lrow) * SENG + k0 + scol, &Vs[bufi][c * 512]);
      }
    }
  };

  stage(0, 0);
  __syncthreads();  // buf0 staged and visible

  const int xr = (rl & 7) << 4;  // byte XOR for swizzled reads

  for (int it = 0; it < 32; ++it) {
    const int cur = it & 1;
    // prefetch next tile into the other buffer; flies under this tile's compute.
    if (it < 31) stage((it + 1) * 64, cur ^ 1);

    // ---- QK^T ----
    const char* KsB = (const char*)Ks[cur];
    f32x4 s[4];
#pragma unroll
    for (int t = 0; t < 4; ++t) {
      const char* kb = KsB + (t * 16 + rl) * 128;
      bf16x8 kf0 = *(const bf16x8*)(kb + ((gl * 16) ^ xr));
      bf16x8 kf1 = *(const bf16x8*)(kb + ((64 + gl * 16) ^ xr));
      f32x4 z = {};
      z = __builtin_amdgcn_mfma_f32_16x16x32_bf16(qf0, kf0, z, 0, 0, 0);
      z = __builtin_amdgcn_mfma_f32_16x16x32_bf16(qf1, kf1, z, 0, 0, 0);
      s[t] = z;
    }

    // ---- online softmax (round-1 verbatim: rescale every iteration) ----
    float al[4];
#pragma unroll
    for (int r = 0; r < 4; ++r) {
      float v = fmaxf(fmaxf(s[0][r], s[1][r]), fmaxf(s[2][r], s[3][r]));
      v = fmaxf(v, __shfl_xor(v, 1));
      v = fmaxf(v, __shfl_xor(v, 2));
      v = fmaxf(v, __shfl_xor(v, 4));
      v = fmaxf(v, __shfl_xor(v, 8));
      const float mnew = fmaxf(m_run[r], v * Cs);
      al[r] = exp2f(m_run[r] - mnew);
      m_run[r] = mnew;
    }
#pragma unroll
    for (int r = 0; r < 4; ++r) {
      const float m = m_run[r];
      float p0 = exp2f(fmaf(s[0][r], Cs, -m));
      float p1 = exp2f(fmaf(s[1][r], Cs, -m));
      float p2 = exp2f(fmaf(s[2][r], Cs, -m));
      float p3 = exp2f(fmaf(s[3][r], Cs, -m));
      unsigned short* pr = &Plds[w][gl * 4 + r][0];
      pr[rl]      = f2bf(p0);
      pr[16 + rl] = f2bf(p1);
      pr[32 + rl] = f2bf(p2);
      pr[48 + rl] = f2bf(p3);
      float t = (p0 + p1) + (p2 + p3);
      t += __shfl_xor(t, 1);
      t += __shfl_xor(t, 2);
      t += __shfl_xor(t, 4);
      t += __shfl_xor(t, 8);
      l_run[r] = l_run[r] * al[r] + t;
    }
#pragma unroll
    for (int nt = 0; nt < 4; ++nt)
#pragma unroll
      for (int r = 0; r < 4; ++r) o[nt][r] *= al[r];

    // ---- PV ----
    const char* VsB = (const char*)Vs[cur];
#pragma unroll
    for (int ks = 0; ks < 2; ++ks) {
      const bf16x8 pf = *(const bf16x8*)&Plds[w][rl][ks * 32 + gl * 8];
#pragma unroll
      for (int nt = 0; nt < 4; ++nt) {
        const char* vb = VsB + (nt * 16 + rl) * 128;
        bf16x8 vf = *(const bf16x8*)(vb + ((ks * 64 + gl * 16) ^ xr));
        o[nt] = __builtin_amdgcn_mfma_f32_16x16x32_bf16(pf, vf, o[nt], 0, 0, 0);
      }
    }

    // single full barrier: drains prefetch (vmcnt) + all LDS ops, syncs waves.
    __syncthreads();
  }

  unsigned short* ob = att + ((size_t)(b * SCHI + q0)) * E_DIM + h * HD_DIM;
#pragma unroll
  for (int r = 0; r < 4; ++r) {
    const float inv = 1.0f / l_run[r];
#pragma unroll
    for (int nt = 0; nt < 4; ++nt)
      ob[(size_t)(gl * 4 + r) * E_DIM + nt * 16 + rl] = f2bf(o[nt][r] * inv);
  }
}

extern "C" void kernel_launch(void* const* d_in, const int* in_sizes, int n_in,
                              void* d_out, int out_size, void* d_ws, size_t ws_size,
                              hipStream_t stream) {
  const float* eng = (const float*)d_in[0];
  const float* chi = (const float*)d_in[1];
  const float* Wq = (const float*)d_in[2];
  const float* Wk = (const float*)d_in[3];
  const float* Wv = (const float*)d_in[4];
  const float* Wo = (const float*)d_in[5];
  float* out = (float*)d_out;

  char* ws = (char*)d_ws;
  const size_t MB = 1024 * 1024;
  unsigned short* WqT = (unsigned short*)(ws + 0 * MB);    // 2 MB
  unsigned short* WkT = (unsigned short*)(ws + 2 * MB);    // 2 MB
  unsigned short* WvT = (unsigned short*)(ws + 4 * MB);    // 2 MB
  unsigned short* WoT = (unsigned short*)(ws + 6 * MB);    // 2 MB
  unsigned short* Xc = (unsigned short*)(ws + 8 * MB);     // 16 MB (reused as att)
  unsigned short* Xe = (unsigned short*)(ws + 24 * MB);    // 32 MB
  unsigned short* Qh = (unsigned short*)(ws + 56 * MB);    // 16 MB
  unsigned short* Kh = (unsigned short*)(ws + 72 * MB);    // 32 MB
  unsigned short* Vt = (unsigned short*)(ws + 104 * MB);   // 32 MB  -> total 136 MB
  unsigned short* att = Xc;  // Xc dead after Q-GEMM

  pack_w_qkv<<<4096, 256, 0, stream>>>(Wq, WqT);
  pack_w_qkv<<<4096, 256, 0, stream>>>(Wk, WkT);
  pack_w_qkv<<<4096, 256, 0, stream>>>(Wv, WvT);
  pack_wo<<<4096, 256, 0, stream>>>(Wo, WoT);

  cast_bf16_k<<<(B_NUM * SCHI * E_DIM / 8) / 256, 256, 0, stream>>>(chi, Xc, B_NUM * SCHI * E_DIM);
  cast_bf16_k<<<(B_NUM * SENG * E_DIM / 8) / 256, 256, 0, stream>>>(eng, Xe, B_NUM * SENG * E_DIM);

  gemm_bt<3><<<dim3(8, 64), 256, 0, stream>>>(Xc, WqT, (void*)Qh, B_NUM * SCHI, E_DIM, E_DIM);
  gemm_bt<4><<<dim3(8, 128), 256, 0, stream>>>(Xe, WkT, (void*)Kh, B_NUM * SENG, E_DIM, E_DIM);
  gemm_bt<2><<<dim3(8, 128), 256, 0, stream>>>(Xe, WvT, (void*)Vt, B_NUM * SENG, E_DIM, E_DIM);

  flash_attn<<<dim3(128, 16), 256, 0, stream>>>(Qh, Kh, Vt, att);

  gemm_bt<1><<<dim3(8, 64), 256, 0, stream>>>(att, WoT, (void*)out, B_NUM * SCHI, E_DIM, E_DIM);
}

// Round 7
// 517.305 us; speedup vs baseline: 1.5422x; 1.1299x over previous
//
#include <hip/hip_runtime.h>
#include <hip/hip_bf16.h>
#include <stdint.h>

#define E_DIM 1024
#define H_NUM 16
#define HD_DIM 64
#define B_NUM 8
#define SENG 2048
#define SCHI 1024

typedef __attribute__((ext_vector_type(4))) float f32x4;
typedef __attribute__((ext_vector_type(8))) short bf16x8;
typedef __attribute__((ext_vector_type(8))) unsigned short u16x8;
typedef __attribute__((ext_vector_type(4))) unsigned short u16x4;

__device__ __forceinline__ unsigned short f2bf(float f) {
  unsigned int u = __builtin_bit_cast(unsigned int, f);
  u = (u + 0x7fffu + ((u >> 16) & 1u)) >> 16;  // RNE
  return (unsigned short)u;
}

__device__ __forceinline__ void gload_lds16(const void* g, void* l) {
  __builtin_amdgcn_global_load_lds(
      (const __attribute__((address_space(1))) unsigned int*)g,
      (__attribute__((address_space(3))) unsigned int*)l, 16, 0, 0);
}

// ---------------- f32 -> bf16 cast (8 elems/thread) ----------------
__global__ __launch_bounds__(256) void cast_bf16_k(const float* __restrict__ in,
                                                   unsigned short* __restrict__ out,
                                                   int n) {
  int i = (blockIdx.x * 256 + threadIdx.x) * 8;
  if (i >= n) return;
  float4 a = *(const float4*)(in + i);
  float4 b = *(const float4*)(in + i + 4);
  u16x8 v;
  v[0] = f2bf(a.x); v[1] = f2bf(a.y); v[2] = f2bf(a.z); v[3] = f2bf(a.w);
  v[4] = f2bf(b.x); v[5] = f2bf(b.y); v[6] = f2bf(b.z); v[7] = f2bf(b.w);
  *(u16x8*)(out + i) = v;
}

// ---- Wq/Wk/Wv [H][E][HD] f32 -> WT [N=h*64+d][K=e] bf16 (B^T layout) ----
__global__ __launch_bounds__(256) void pack_w_qkv(const float* __restrict__ w,
                                                  unsigned short* __restrict__ wt) {
  int t = blockIdx.x * 256 + threadIdx.x;  // t = n*1024 + e
  int e = t & 1023;
  int n = t >> 10;
  int h = n >> 6, d = n & 63;
  wt[t] = f2bf(w[(h * E_DIM + e) * HD_DIM + d]);
}

// ---- Wo [E][E] f32 -> WoT [n][k] = Wo[k][n] bf16 ----
__global__ __launch_bounds__(256) void pack_wo(const float* __restrict__ w,
                                               unsigned short* __restrict__ wt) {
  int t = blockIdx.x * 256 + threadIdx.x;  // t = n*1024 + k
  int k = t & 1023;
  int n = t >> 10;
  wt[t] = f2bf(w[k * E_DIM + n]);
}

// ---------------- GEMM: C = A[M,K] * Bt[N,K]^T ----------------
// MODE 1: C f32 row-major [M][N]
// MODE 2: C bf16 into Vt[bh][d][kk]   (row=b*SENG+kk, col=h*64+d)
// MODE 3: C bf16 into Qh[bh][q][d]    (row=b*SCHI+q,  col=h*64+d)
// MODE 4: C bf16 into Kh[bh][kk][d]   (row=b*SENG+kk, col=h*64+d)
template <int MODE>
__global__ __launch_bounds__(256) void gemm_bt(const unsigned short* __restrict__ A,
                                               const unsigned short* __restrict__ Bt,
                                               void* __restrict__ Cv,
                                               int M, int N, int K) {
  __shared__ unsigned short As[128 * 32];
  __shared__ unsigned short Bs[128 * 32];
  const int tid = threadIdx.x;
  const int w = tid >> 6, lane = tid & 63;
  const int bm = blockIdx.y, bn = blockIdx.x;
  const int wm = w >> 1, wn = w & 1;
  const int rl = lane & 15, gl = lane >> 4;
  f32x4 acc[4][4] = {};

  const int lr = lane >> 2, lc = lane & 3;  // 16 rows x 4 chunks per wave-load
  const unsigned short* Ag = A + (size_t)(bm * 128 + w * 32 + lr) * K + lc * 8;
  const unsigned short* Bg = Bt + (size_t)(bn * 128 + w * 32 + lr) * K + lc * 8;
  unsigned short* Asw = As + w * 32 * 32;  // wave-uniform LDS base
  unsigned short* Bsw = Bs + w * 32 * 32;

  for (int kt = 0; kt < K; kt += 32) {
    gload_lds16(Ag + kt, Asw);
    gload_lds16(Ag + kt + 16 * K, Asw + 16 * 32);
    gload_lds16(Bg + kt, Bsw);
    gload_lds16(Bg + kt + 16 * K, Bsw + 16 * 32);
    __syncthreads();
    bf16x8 af[4], bfr[4];
#pragma unroll
    for (int mt = 0; mt < 4; ++mt)
      af[mt] = *(const bf16x8*)&As[(wm * 64 + mt * 16 + rl) * 32 + gl * 8];
#pragma unroll
    for (int nt = 0; nt < 4; ++nt)
      bfr[nt] = *(const bf16x8*)&Bs[(wn * 64 + nt * 16 + rl) * 32 + gl * 8];
#pragma unroll
    for (int mt = 0; mt < 4; ++mt)
#pragma unroll
      for (int nt = 0; nt < 4; ++nt)
        acc[mt][nt] =
            __builtin_amdgcn_mfma_f32_16x16x32_bf16(af[mt], bfr[nt], acc[mt][nt], 0, 0, 0);
    __syncthreads();
  }

#pragma unroll
  for (int mt = 0; mt < 4; ++mt)
#pragma unroll
    for (int nt = 0; nt < 4; ++nt) {
      const int row0 = bm * 128 + wm * 64 + mt * 16 + gl * 4;
      const int col = bn * 128 + wn * 64 + nt * 16 + rl;
      if (MODE == 1) {
        float* C = (float*)Cv;
#pragma unroll
        for (int r = 0; r < 4; ++r) C[(size_t)(row0 + r) * N + col] = acc[mt][nt][r];
      } else if (MODE == 2) {
        unsigned short* Vt = (unsigned short*)Cv;
        const int b = row0 >> 11, kk = row0 & 2047;
        const int h = col >> 6, d = col & 63;
        u16x4 pk;
#pragma unroll
        for (int r = 0; r < 4; ++r) pk[r] = f2bf(acc[mt][nt][r]);
        *(u16x4*)(Vt + (size_t)((b * 16 + h) * 64 + d) * SENG + kk) = pk;
      } else if (MODE == 3) {
        unsigned short* Qh = (unsigned short*)Cv;
        const int b = row0 >> 10, q = row0 & 1023;
        const int h = col >> 6, d = col & 63;
        unsigned short* p = Qh + (((size_t)(b * 16 + h) * SCHI + q) * HD_DIM + d);
#pragma unroll
        for (int r = 0; r < 4; ++r) p[(size_t)r * HD_DIM] = f2bf(acc[mt][nt][r]);
      } else {  // MODE 4
        unsigned short* Kh = (unsigned short*)Cv;
        const int b = row0 >> 11, kk = row0 & 2047;
        const int h = col >> 6, d = col & 63;
        unsigned short* p = Kh + (((size_t)(b * 16 + h) * SENG + kk) * HD_DIM + d);
#pragma unroll
        for (int r = 0; r < 4; ++r) p[(size_t)r * HD_DIM] = f2bf(acc[mt][nt][r]);
      }
    }
}

// ---------------- flash attention ----------------
// grid: (bh=128, qb=16), 256 thr (4 waves x 16 q-rows). KB=64 keys/iter.
// Sync structure = round-6 verified (ONE __syncthreads per iter, race-free).
// This round (VALU cuts only; VALUBusy was 67%, MfmaUtil 11%):
//  - defer-rescale THR=8 (skip 16-shfl max reduce + rescale when quiescent)
//  - deferred l-reduction (per-lane partials, one group-reduce at end)
//  - v_cvt_pk_bf16_f32 for P->bf16 (l sums the QUANTIZED P -> numerator
//    and denominator consistent regardless of cvt rounding mode)
__global__ __launch_bounds__(256) void flash_attn(const unsigned short* __restrict__ Qh,
                                                  const unsigned short* __restrict__ Kh,
                                                  const unsigned short* __restrict__ Vt,
                                                  unsigned short* __restrict__ att) {
  const int bh = blockIdx.x, qb = blockIdx.y;
  const int b = bh >> 4, h = bh & 15;
  const int w = threadIdx.x >> 6, lane = threadIdx.x & 63;
  const int rl = lane & 15, gl = lane >> 4;

  __shared__ unsigned short Ks[2][4096];      // 2 x 8KB: [krow 64][d 64] swizzled
  __shared__ unsigned short Vs[2][4096];      // 2 x 8KB: [d 64][k 64]   swizzled
  __shared__ unsigned short Plds[4][16][72];  // per-wave P, padded rows

  const unsigned short* Kb = Kh + (size_t)bh * (SENG * HD_DIM);
  const unsigned short* Vb = Vt + (size_t)bh * (HD_DIM * SENG);

  const int q0 = qb * 64 + w * 16;
  const unsigned short* Qp = Qh + ((size_t)bh * SCHI + q0 + rl) * HD_DIM + gl * 8;
  const bf16x8 qf0 = *(const bf16x8*)Qp;
  const bf16x8 qf1 = *(const bf16x8*)(Qp + 32);

  // staging geometry: 16 chunks of 1KB (8 K + 8 V), wave w -> 4 chunks.
  // LDS[r][u] = G[r][u^r] in 16B units within each 8-row chunk.
  const int lrow = lane >> 3;                          // 0..7 within chunk
  const int scol = ((lane & 7) ^ lrow) << 3;           // u16 units (swizzled col)

  f32x4 o[4] = {};
  float m_run[4], lp[4];
#pragma unroll
  for (int r = 0; r < 4; ++r) { m_run[r] = -1e30f; lp[r] = 0.f; }
  const float Cs = 0.125f * 1.44269504f;  // 1/sqrt(64) * log2(e)

  auto stage = [&](int k0, int bufi) {
    if (w < 2) {
      const int c0 = w * 4;
#pragma unroll
      for (int j = 0; j < 4; ++j) {
        const int c = c0 + j;
        gload_lds16(Kb + (size_t)(k0 + c * 8 + lrow) * HD_DIM + scol, &Ks[bufi][c * 512]);
      }
    } else {
      const int c0 = (w - 2) * 4;
#pragma unroll
      for (int j = 0; j < 4; ++j) {
        const int c = c0 + j;
        gload_lds16(Vb + (size_t)(c * 8 + lrow) * SENG + k0 + scol, &Vs[bufi][c * 512]);
      }
    }
  };

  stage(0, 0);
  __syncthreads();  // buf0 staged and visible

  const int xr = (rl & 7) << 4;  // byte XOR for swizzled reads

  for (int it = 0; it < 32; ++it) {
    const int cur = it & 1;
    // prefetch next tile into the other buffer; flies under this tile's compute.
    if (it < 31) stage((it + 1) * 64, cur ^ 1);

    // ---- QK^T ----
    const char* KsB = (const char*)Ks[cur];
    f32x4 s[4];
#pragma unroll
    for (int t = 0; t < 4; ++t) {
      const char* kb = KsB + (t * 16 + rl) * 128;
      bf16x8 kf0 = *(const bf16x8*)(kb + ((gl * 16) ^ xr));
      bf16x8 kf1 = *(const bf16x8*)(kb + ((64 + gl * 16) ^ xr));
      f32x4 z = {};
      z = __builtin_amdgcn_mfma_f32_16x16x32_bf16(qf0, kf0, z, 0, 0, 0);
      z = __builtin_amdgcn_mfma_f32_16x16x32_bf16(qf1, kf1, z, 0, 0, 0);
      s[t] = z;
    }

    // ---- online softmax with defer-rescale (THR=8 log2 units) ----
    float vmax[4];
#pragma unroll
    for (int r = 0; r < 4; ++r)
      vmax[r] = fmaxf(fmaxf(s[0][r], s[1][r]), fmaxf(s[2][r], s[3][r]));
    const int need =
        (vmax[0] * Cs > m_run[0] + 8.f) | (vmax[1] * Cs > m_run[1] + 8.f) |
        (vmax[2] * Cs > m_run[2] + 8.f) | (vmax[3] * Cs > m_run[3] + 8.f);
    if (__any(need)) {
#pragma unroll
      for (int r = 0; r < 4; ++r) {
        float v = vmax[r];
        v = fmaxf(v, __shfl_xor(v, 1));
        v = fmaxf(v, __shfl_xor(v, 2));
        v = fmaxf(v, __shfl_xor(v, 4));
        v = fmaxf(v, __shfl_xor(v, 8));
        const float mnew = fmaxf(m_run[r], v * Cs);
        const float al = exp2f(m_run[r] - mnew);
        m_run[r] = mnew;
        lp[r] *= al;
        o[0][r] *= al; o[1][r] *= al; o[2][r] *= al; o[3][r] *= al;
      }
    }

#pragma unroll
    for (int r = 0; r < 4; ++r) {
      const float m = m_run[r];
      float p0 = exp2f(fmaf(s[0][r], Cs, -m));
      float p1 = exp2f(fmaf(s[1][r], Cs, -m));
      float p2 = exp2f(fmaf(s[2][r], Cs, -m));
      float p3 = exp2f(fmaf(s[3][r], Cs, -m));
      unsigned int r01, r23;
      asm("v_cvt_pk_bf16_f32 %0, %1, %2" : "=v"(r01) : "v"(p0), "v"(p1));
      asm("v_cvt_pk_bf16_f32 %0, %1, %2" : "=v"(r23) : "v"(p2), "v"(p3));
      unsigned short* pr = &Plds[w][gl * 4 + r][0];
      pr[rl]      = (unsigned short)r01;
      pr[16 + rl] = (unsigned short)(r01 >> 16);
      pr[32 + rl] = (unsigned short)r23;
      pr[48 + rl] = (unsigned short)(r23 >> 16);
      // l accumulates the QUANTIZED P (consistent with the PV numerator)
      const float q0 = __builtin_bit_cast(float, r01 << 16);
      const float q1 = __builtin_bit_cast(float, r01 & 0xffff0000u);
      const float q2 = __builtin_bit_cast(float, r23 << 16);
      const float q3 = __builtin_bit_cast(float, r23 & 0xffff0000u);
      lp[r] += (q0 + q1) + (q2 + q3);
    }

    // ---- PV ----
    const char* VsB = (const char*)Vs[cur];
#pragma unroll
    for (int ks = 0; ks < 2; ++ks) {
      const bf16x8 pf = *(const bf16x8*)&Plds[w][rl][ks * 32 + gl * 8];
#pragma unroll
      for (int nt = 0; nt < 4; ++nt) {
        const char* vb = VsB + (nt * 16 + rl) * 128;
        bf16x8 vf = *(const bf16x8*)(vb + ((ks * 64 + gl * 16) ^ xr));
        o[nt] = __builtin_amdgcn_mfma_f32_16x16x32_bf16(pf, vf, o[nt], 0, 0, 0);
      }
    }

    // single full barrier: drains prefetch (vmcnt) + all LDS ops, syncs waves.
    __syncthreads();
  }

  unsigned short* ob = att + ((size_t)(b * SCHI + q0)) * E_DIM + h * HD_DIM;
#pragma unroll
  for (int r = 0; r < 4; ++r) {
    float t2 = lp[r];
    t2 += __shfl_xor(t2, 1);
    t2 += __shfl_xor(t2, 2);
    t2 += __shfl_xor(t2, 4);
    t2 += __shfl_xor(t2, 8);
    const float inv = 1.0f / t2;
#pragma unroll
    for (int nt = 0; nt < 4; ++nt)
      ob[(size_t)(gl * 4 + r) * E_DIM + nt * 16 + rl] = f2bf(o[nt][r] * inv);
  }
}

extern "C" void kernel_launch(void* const* d_in, const int* in_sizes, int n_in,
                              void* d_out, int out_size, void* d_ws, size_t ws_size,
                              hipStream_t stream) {
  const float* eng = (const float*)d_in[0];
  const float* chi = (const float*)d_in[1];
  const float* Wq = (const float*)d_in[2];
  const float* Wk = (const float*)d_in[3];
  const float* Wv = (const float*)d_in[4];
  const float* Wo = (const float*)d_in[5];
  float* out = (float*)d_out;

  char* ws = (char*)d_ws;
  const size_t MB = 1024 * 1024;
  unsigned short* WqT = (unsigned short*)(ws + 0 * MB);    // 2 MB
  unsigned short* WkT = (unsigned short*)(ws + 2 * MB);    // 2 MB
  unsigned short* WvT = (unsigned short*)(ws + 4 * MB);    // 2 MB
  unsigned short* WoT = (unsigned short*)(ws + 6 * MB);    // 2 MB
  unsigned short* Xc = (unsigned short*)(ws + 8 * MB);     // 16 MB (reused as att)
  unsigned short* Xe = (unsigned short*)(ws + 24 * MB);    // 32 MB
  unsigned short* Qh = (unsigned short*)(ws + 56 * MB);    // 16 MB
  unsigned short* Kh = (unsigned short*)(ws + 72 * MB);    // 32 MB
  unsigned short* Vt = (unsigned short*)(ws + 104 * MB);   // 32 MB  -> total 136 MB
  unsigned short* att = Xc;  // Xc dead after Q-GEMM

  pack_w_qkv<<<4096, 256, 0, stream>>>(Wq, WqT);
  pack_w_qkv<<<4096, 256, 0, stream>>>(Wk, WkT);
  pack_w_qkv<<<4096, 256, 0, stream>>>(Wv, WvT);
  pack_wo<<<4096, 256, 0, stream>>>(Wo, WoT);

  cast_bf16_k<<<(B_NUM * SCHI * E_DIM / 8) / 256, 256, 0, stream>>>(chi, Xc, B_NUM * SCHI * E_DIM);
  cast_bf16_k<<<(B_NUM * SENG * E_DIM / 8) / 256, 256, 0, stream>>>(eng, Xe, B_NUM * SENG * E_DIM);

  gemm_bt<3><<<dim3(8, 64), 256, 0, stream>>>(Xc, WqT, (void*)Qh, B_NUM * SCHI, E_DIM, E_DIM);
  gemm_bt<4><<<dim3(8, 128), 256, 0, stream>>>(Xe, WkT, (void*)Kh, B_NUM * SENG, E_DIM, E_DIM);
  gemm_bt<2><<<dim3(8, 128), 256, 0, stream>>>(Xe, WvT, (void*)Vt, B_NUM * SENG, E_DIM, E_DIM);

  flash_attn<<<dim3(128, 16), 256, 0, stream>>>(Qh, Kh, Vt, att);

  gemm_bt<1><<<dim3(8, 64), 256, 0, stream>>>(att, WoT, (void*)out, B_NUM * SCHI, E_DIM, E_DIM);
}

// Round 8
// 505.005 us; speedup vs baseline: 1.5798x; 1.0244x over previous
//
#include <hip/hip_runtime.h>
#include <hip/hip_bf16.h>
#include <stdint.h>

#define E_DIM 1024
#define H_NUM 16
#define HD_DIM 64
#define B_NUM 8
#define SENG 2048
#define SCHI 1024

typedef __attribute__((ext_vector_type(4))) float f32x4;
typedef __attribute__((ext_vector_type(16))) float f32x16;
typedef __attribute__((ext_vector_type(8))) short bf16x8;
typedef __attribute__((ext_vector_type(8))) unsigned short u16x8;
typedef __attribute__((ext_vector_type(4))) unsigned short u16x4;
typedef __attribute__((ext_vector_type(4))) unsigned int u32x4;

__device__ __forceinline__ unsigned short f2bf(float f) {
  unsigned int u = __builtin_bit_cast(unsigned int, f);
  u = (u + 0x7fffu + ((u >> 16) & 1u)) >> 16;  // RNE
  return (unsigned short)u;
}

__device__ __forceinline__ unsigned int cvtpk_bf16(float a, float b) {
  unsigned int r;
  asm("v_cvt_pk_bf16_f32 %0, %1, %2" : "=v"(r) : "v"(a), "v"(b));
  return r;
}

__device__ __forceinline__ void gload_lds16(const void* g, void* l) {
  __builtin_amdgcn_global_load_lds(
      (const __attribute__((address_space(1))) unsigned int*)g,
      (__attribute__((address_space(3))) unsigned int*)l, 16, 0, 0);
}

// ---------------- f32 -> bf16 cast (8 elems/thread) ----------------
__global__ __launch_bounds__(256) void cast_bf16_k(const float* __restrict__ in,
                                                   unsigned short* __restrict__ out,
                                                   int n) {
  int i = (blockIdx.x * 256 + threadIdx.x) * 8;
  if (i >= n) return;
  float4 a = *(const float4*)(in + i);
  float4 b = *(const float4*)(in + i + 4);
  u16x8 v;
  v[0] = f2bf(a.x); v[1] = f2bf(a.y); v[2] = f2bf(a.z); v[3] = f2bf(a.w);
  v[4] = f2bf(b.x); v[5] = f2bf(b.y); v[6] = f2bf(b.z); v[7] = f2bf(b.w);
  *(u16x8*)(out + i) = v;
}

// ---- Wq/Wk/Wv [H][E][HD] f32 -> WT [N=h*64+d][K=e] bf16 (B^T layout) ----
__global__ __launch_bounds__(256) void pack_w_qkv(const float* __restrict__ w,
                                                  unsigned short* __restrict__ wt) {
  int t = blockIdx.x * 256 + threadIdx.x;  // t = n*1024 + e
  int e = t & 1023;
  int n = t >> 10;
  int h = n >> 6, d = n & 63;
  wt[t] = f2bf(w[(h * E_DIM + e) * HD_DIM + d]);
}

// ---- Wo [E][E] f32 -> WoT [n][k] = Wo[k][n] bf16 ----
__global__ __launch_bounds__(256) void pack_wo(const float* __restrict__ w,
                                               unsigned short* __restrict__ wt) {
  int t = blockIdx.x * 256 + threadIdx.x;  // t = n*1024 + k
  int k = t & 1023;
  int n = t >> 10;
  wt[t] = f2bf(w[k * E_DIM + n]);
}

// ---------------- GEMM: C = A[M,K] * Bt[N,K]^T ----------------
// MODE 1: C f32 row-major [M][N]
// MODE 2: C bf16 into Vt[bh][d][kk]   (row=b*SENG+kk, col=h*64+d)
// MODE 3: C bf16 into Qh[bh][q][d]    (row=b*SCHI+q,  col=h*64+d)
// MODE 4: C bf16 into Kh[bh][kk][d]   (row=b*SENG+kk, col=h*64+d)
template <int MODE>
__global__ __launch_bounds__(256) void gemm_bt(const unsigned short* __restrict__ A,
                                               const unsigned short* __restrict__ Bt,
                                               void* __restrict__ Cv,
                                               int M, int N, int K) {
  __shared__ unsigned short As[128 * 32];
  __shared__ unsigned short Bs[128 * 32];
  const int tid = threadIdx.x;
  const int w = tid >> 6, lane = tid & 63;
  const int bm = blockIdx.y, bn = blockIdx.x;
  const int wm = w >> 1, wn = w & 1;
  const int rl = lane & 15, gl = lane >> 4;
  f32x4 acc[4][4] = {};

  const int lr = lane >> 2, lc = lane & 3;  // 16 rows x 4 chunks per wave-load
  const unsigned short* Ag = A + (size_t)(bm * 128 + w * 32 + lr) * K + lc * 8;
  const unsigned short* Bg = Bt + (size_t)(bn * 128 + w * 32 + lr) * K + lc * 8;
  unsigned short* Asw = As + w * 32 * 32;  // wave-uniform LDS base
  unsigned short* Bsw = Bs + w * 32 * 32;

  for (int kt = 0; kt < K; kt += 32) {
    gload_lds16(Ag + kt, Asw);
    gload_lds16(Ag + kt + 16 * K, Asw + 16 * 32);
    gload_lds16(Bg + kt, Bsw);
    gload_lds16(Bg + kt + 16 * K, Bsw + 16 * 32);
    __syncthreads();
    bf16x8 af[4], bfr[4];
#pragma unroll
    for (int mt = 0; mt < 4; ++mt)
      af[mt] = *(const bf16x8*)&As[(wm * 64 + mt * 16 + rl) * 32 + gl * 8];
#pragma unroll
    for (int nt = 0; nt < 4; ++nt)
      bfr[nt] = *(const bf16x8*)&Bs[(wn * 64 + nt * 16 + rl) * 32 + gl * 8];
#pragma unroll
    for (int mt = 0; mt < 4; ++mt)
#pragma unroll
      for (int nt = 0; nt < 4; ++nt)
        acc[mt][nt] =
            __builtin_amdgcn_mfma_f32_16x16x32_bf16(af[mt], bfr[nt], acc[mt][nt], 0, 0, 0);
    __syncthreads();
  }

#pragma unroll
  for (int mt = 0; mt < 4; ++mt)
#pragma unroll
    for (int nt = 0; nt < 4; ++nt) {
      const int row0 = bm * 128 + wm * 64 + mt * 16 + gl * 4;
      const int col = bn * 128 + wn * 64 + nt * 16 + rl;
      if (MODE == 1) {
        float* C = (float*)Cv;
#pragma unroll
        for (int r = 0; r < 4; ++r) C[(size_t)(row0 + r) * N + col] = acc[mt][nt][r];
      } else if (MODE == 2) {
        unsigned short* Vt = (unsigned short*)Cv;
        const int b = row0 >> 11, kk = row0 & 2047;
        const int h = col >> 6, d = col & 63;
        u16x4 pk;
#pragma unroll
        for (int r = 0; r < 4; ++r) pk[r] = f2bf(acc[mt][nt][r]);
        *(u16x4*)(Vt + (size_t)((b * 16 + h) * 64 + d) * SENG + kk) = pk;
      } else if (MODE == 3) {
        unsigned short* Qh = (unsigned short*)Cv;
        const int b = row0 >> 10, q = row0 & 1023;
        const int h = col >> 6, d = col & 63;
        unsigned short* p = Qh + (((size_t)(b * 16 + h) * SCHI + q) * HD_DIM + d);
#pragma unroll
        for (int r = 0; r < 4; ++r) p[(size_t)r * HD_DIM] = f2bf(acc[mt][nt][r]);
      } else {  // MODE 4
        unsigned short* Kh = (unsigned short*)Cv;
        const int b = row0 >> 11, kk = row0 & 2047;
        const int h = col >> 6, d = col & 63;
        unsigned short* p = Kh + (((size_t)(b * 16 + h) * SENG + kk) * HD_DIM + d);
#pragma unroll
        for (int r = 0; r < 4; ++r) p[(size_t)r * HD_DIM] = f2bf(acc[mt][nt][r]);
      }
    }
}

// ---------------- flash attention, swapped-operand 32x32 ----------------
// grid: (bh=128, qb=8), 256 thr = 4 waves x 32 q-rows. KB=64 keys/iter.
// St = mfma_32x32x16(K_frag, Q_frag): col = lane&31 = q -> each lane owns
// ONE q-row; 32 P-values live in registers. Softmax = in-lane tree + one
// shfl_xor(32). P -> PV B-frags via 16 cvt_pk + 8 permlane32_swap (no LDS).
// PV = mfma(V^T_frag, P_frag): col = q again -> rescale stays lane-scalar.
// K/V staging + XOR swizzle + one __syncthreads/iter: verbatim from r6/r7
// (race-free verified). Defer-rescale THR=8 (r7-verified numerics).
__global__ __launch_bounds__(256) void flash_attn(const unsigned short* __restrict__ Qh,
                                                  const unsigned short* __restrict__ Kh,
                                                  const unsigned short* __restrict__ Vt,
                                                  unsigned short* __restrict__ att) {
  const int bh = blockIdx.x, qb = blockIdx.y;
  const int b = bh >> 4, h = bh & 15;
  const int w = threadIdx.x >> 6, lane = threadIdx.x & 63;
  const int lq = lane & 31, hi = lane >> 5, l7 = lane & 7;

  __shared__ unsigned short Ks[2][4096];  // 2 x 8KB: [key 64][d 64] swizzled
  __shared__ unsigned short Vs[2][4096];  // 2 x 8KB: [d 64][key 64] swizzled

  const unsigned short* Kb = Kh + (size_t)bh * (SENG * HD_DIM);
  const unsigned short* Vb = Vt + (size_t)bh * (HD_DIM * SENG);

  // Q fragments: lane holds Q[q_row][dc*16 + hi*8 .. +8] for dc=0..3
  const int q_row = qb * 128 + w * 32 + lq;
  const unsigned short* Qp = Qh + ((size_t)bh * SCHI + q_row) * HD_DIM + hi * 8;
  bf16x8 qf[4];
#pragma unroll
  for (int dc = 0; dc < 4; ++dc) qf[dc] = *(const bf16x8*)(Qp + dc * 16);

  // staging geometry (r6-verified): LDS[r][block b] = G[r][b ^ (r&7)], 16B blocks
  const int lrow = lane >> 3;
  const int scol = ((lane & 7) ^ lrow) << 3;  // u16 units

  auto stage = [&](int k0, int bufi) {
    if (w < 2) {
      const int c0 = w * 4;
#pragma unroll
      for (int j = 0; j < 4; ++j) {
        const int c = c0 + j;
        gload_lds16(Kb + (size_t)(k0 + c * 8 + lrow) * HD_DIM + scol, &Ks[bufi][c * 512]);
      }
    } else {
      const int c0 = (w - 2) * 4;
#pragma unroll
      for (int j = 0; j < 4; ++j) {
        const int c = c0 + j;
        gload_lds16(Vb + (size_t)(c * 8 + lrow) * SENG + k0 + scol, &Vs[bufi][c * 512]);
      }
    }
  };

  // swizzled read offsets (bytes), precomputed per lane
  int koff[4];
#pragma unroll
  for (int dc = 0; dc < 4; ++dc)
    koff[dc] = lq * 128 + (((2 * dc + hi) ^ l7) << 4);
  int voff[2][4];
#pragma unroll
  for (int dt = 0; dt < 2; ++dt)
#pragma unroll
    for (int kc = 0; kc < 4; ++kc)
      voff[dt][kc] = (dt * 32 + lq) * 128 + (((2 * kc + hi) ^ l7) << 4);

  f32x16 o[2] = {};
  float m_run = -1e30f, lp = 0.f;
  const float Cs = 0.125f * 1.44269504f;  // 1/sqrt(64) * log2(e)

  stage(0, 0);
  __syncthreads();

  for (int it = 0; it < 32; ++it) {
    const int cur = it & 1;
    if (it < 31) stage((it + 1) * 64, cur ^ 1);

    // ---- QK^T (swapped): St[k][q], lane owns col q ----
    const char* KsB = (const char*)Ks[cur];
    f32x16 st0 = {}, st1 = {};
#pragma unroll
    for (int dc = 0; dc < 4; ++dc) {
      bf16x8 kf0 = *(const bf16x8*)(KsB + koff[dc]);
      bf16x8 kf1 = *(const bf16x8*)(KsB + 4096 + koff[dc]);
      st0 = __builtin_amdgcn_mfma_f32_32x32x16_bf16(kf0, qf[dc], st0, 0, 0, 0);
      st1 = __builtin_amdgcn_mfma_f32_32x32x16_bf16(kf1, qf[dc], st1, 0, 0, 0);
    }

    // ---- in-lane max + cross-half, defer-rescale THR=8 ----
    float mbuf[16];
#pragma unroll
    for (int r = 0; r < 16; ++r) mbuf[r] = fmaxf(st0[r], st1[r]);
#pragma unroll
    for (int s2 = 8; s2 > 0; s2 >>= 1)
#pragma unroll
      for (int i = 0; i < 8; ++i)
        if (i < s2) mbuf[i] = fmaxf(mbuf[i], mbuf[i + s2]);
    float v = mbuf[0];
    v = fmaxf(v, __shfl_xor(v, 32));
    if (__any(v * Cs > m_run + 8.f)) {
      const float mnew = fmaxf(m_run, v * Cs);
      const float al = exp2f(m_run - mnew);
      m_run = mnew;
      lp *= al;
      o[0] *= al;
      o[1] *= al;
    }

    // ---- P = exp2(S*Cs - m), per-lane row; sum into lp ----
    float p0a[16], p1a[16];
#pragma unroll
    for (int r = 0; r < 16; ++r) p0a[r] = exp2f(fmaf(st0[r], Cs, -m_run));
#pragma unroll
    for (int r = 0; r < 16; ++r) p1a[r] = exp2f(fmaf(st1[r], Cs, -m_run));
    float sbuf[16];
#pragma unroll
    for (int r = 0; r < 16; ++r) sbuf[r] = p0a[r] + p1a[r];
#pragma unroll
    for (int s2 = 8; s2 > 0; s2 >>= 1)
#pragma unroll
      for (int i = 0; i < 8; ++i)
        if (i < s2) sbuf[i] += sbuf[i + s2];
    lp += sbuf[0];

    // ---- build PV B-frags in-register: 16 cvt_pk + 8 permlane32_swap ----
    // pa[kc] elements e: key = kc*16 + hi*8 + e. U = regs[8kc..+3], V = regs[8kc+4..+7].
    bf16x8 pa[4];
#pragma unroll
    for (int kc = 0; kc < 4; ++kc) {
      const float* ps = (kc < 2) ? p0a : p1a;
      const int base = (kc & 1) * 8;
      unsigned int ua = cvtpk_bf16(ps[base + 0], ps[base + 1]);
      unsigned int ub = cvtpk_bf16(ps[base + 2], ps[base + 3]);
      unsigned int va = cvtpk_bf16(ps[base + 4], ps[base + 5]);
      unsigned int vb = cvtpk_bf16(ps[base + 6], ps[base + 7]);
      asm("v_permlane32_swap_b32 %0, %1" : "+v"(ua), "+v"(va));
      asm("v_permlane32_swap_b32 %0, %1" : "+v"(ub), "+v"(vb));
      pa[kc] = __builtin_bit_cast(bf16x8, (u32x4){ua, ub, va, vb});
    }

    // ---- PV (swapped): O^T[d][q], col = q ----
    const char* VsB = (const char*)Vs[cur];
#pragma unroll
    for (int kc = 0; kc < 4; ++kc) {
#pragma unroll
      for (int dt = 0; dt < 2; ++dt) {
        bf16x8 vf = *(const bf16x8*)(VsB + voff[dt][kc]);
        o[dt] = __builtin_amdgcn_mfma_f32_32x32x16_bf16(vf, pa[kc], o[dt], 0, 0, 0);
      }
    }

    __syncthreads();
  }

  const float lf = lp + __shfl_xor(lp, 32);
  const float inv = 1.0f / lf;
  unsigned short* ob = att + (size_t)(b * SCHI + q_row) * E_DIM + h * HD_DIM;
#pragma unroll
  for (int dt = 0; dt < 2; ++dt)
#pragma unroll
    for (int j = 0; j < 4; ++j) {
      u16x4 pk;
#pragma unroll
      for (int i = 0; i < 4; ++i) pk[i] = f2bf(o[dt][4 * j + i] * inv);
      *(u16x4*)(ob + dt * 32 + 8 * j + 4 * hi) = pk;
    }
}

extern "C" void kernel_launch(void* const* d_in, const int* in_sizes, int n_in,
                              void* d_out, int out_size, void* d_ws, size_t ws_size,
                              hipStream_t stream) {
  const float* eng = (const float*)d_in[0];
  const float* chi = (const float*)d_in[1];
  const float* Wq = (const float*)d_in[2];
  const float* Wk = (const float*)d_in[3];
  const float* Wv = (const float*)d_in[4];
  const float* Wo = (const float*)d_in[5];
  float* out = (float*)d_out;

  char* ws = (char*)d_ws;
  const size_t MB = 1024 * 1024;
  unsigned short* WqT = (unsigned short*)(ws + 0 * MB);    // 2 MB
  unsigned short* WkT = (unsigned short*)(ws + 2 * MB);    // 2 MB
  unsigned short* WvT = (unsigned short*)(ws + 4 * MB);    // 2 MB
  unsigned short* WoT = (unsigned short*)(ws + 6 * MB);    // 2 MB
  unsigned short* Xc = (unsigned short*)(ws + 8 * MB);     // 16 MB (reused as att)
  unsigned short* Xe = (unsigned short*)(ws + 24 * MB);    // 32 MB
  unsigned short* Qh = (unsigned short*)(ws + 56 * MB);    // 16 MB
  unsigned short* Kh = (unsigned short*)(ws + 72 * MB);    // 32 MB
  unsigned short* Vt = (unsigned short*)(ws + 104 * MB);   // 32 MB  -> total 136 MB
  unsigned short* att = Xc;  // Xc dead after Q-GEMM

  pack_w_qkv<<<4096, 256, 0, stream>>>(Wq, WqT);
  pack_w_qkv<<<4096, 256, 0, stream>>>(Wk, WkT);
  pack_w_qkv<<<4096, 256, 0, stream>>>(Wv, WvT);
  pack_wo<<<4096, 256, 0, stream>>>(Wo, WoT);

  cast_bf16_k<<<(B_NUM * SCHI * E_DIM / 8) / 256, 256, 0, stream>>>(chi, Xc, B_NUM * SCHI * E_DIM);
  cast_bf16_k<<<(B_NUM * SENG * E_DIM / 8) / 256, 256, 0, stream>>>(eng, Xe, B_NUM * SENG * E_DIM);

  gemm_bt<3><<<dim3(8, 64), 256, 0, stream>>>(Xc, WqT, (void*)Qh, B_NUM * SCHI, E_DIM, E_DIM);
  gemm_bt<4><<<dim3(8, 128), 256, 0, stream>>>(Xe, WkT, (void*)Kh, B_NUM * SENG, E_DIM, E_DIM);
  gemm_bt<2><<<dim3(8, 128), 256, 0, stream>>>(Xe, WvT, (void*)Vt, B_NUM * SENG, E_DIM, E_DIM);

  flash_attn<<<dim3(128, 8), 256, 0, stream>>>(Qh, Kh, Vt, att);

  gemm_bt<1><<<dim3(8, 64), 256, 0, stream>>>(att, WoT, (void*)out, B_NUM * SCHI, E_DIM, E_DIM);
}